// Round 5
// baseline (226.910 us; speedup 1.0000x reference)
//
#include <hip/hip_runtime.h>
#include <hip/hip_bf16.h>

#define E_DIM 1024
#define NHEAD 16
#define HDIM  64
#define BATCH 4
#define SEQ   2048
#define RQKV  (3 * E_DIM)

typedef __attribute__((ext_vector_type(8))) short bf16x8;
typedef __attribute__((ext_vector_type(4))) float f32x4;
typedef __attribute__((ext_vector_type(16))) float f32x16;

static __device__ __forceinline__ unsigned short bits_of(__hip_bfloat16 h) {
    return *reinterpret_cast<unsigned short*>(&h);
}

static __device__ __forceinline__ void gload_lds16(const void* g, void* l) {
    __builtin_amdgcn_global_load_lds(
        (__attribute__((address_space(1))) void*)g,
        (__attribute__((address_space(3))) void*)l, 16, 0, 0);
}

// ---------------- cast fp32 -> bf16, 4 elems/thread ----------------
__global__ void cast_kernel(const float* __restrict__ in,
                            __hip_bfloat16* __restrict__ out, int n4) {
    int i = blockIdx.x * blockDim.x + threadIdx.x;
    if (i < n4) {
        float4 v = reinterpret_cast<const float4*>(in)[i];
        ushort4 u;
        u.x = bits_of(__float2bfloat16(v.x));
        u.y = bits_of(__float2bfloat16(v.y));
        u.z = bits_of(__float2bfloat16(v.z));
        u.w = bits_of(__float2bfloat16(v.w));
        reinterpret_cast<ushort4*>(out)[i] = u;
    }
}

// fused 4-weight cast: blockIdx.y selects the weight
__global__ void cast4_kernel(const float* __restrict__ w0, const float* __restrict__ w1,
                             const float* __restrict__ w2, const float* __restrict__ w3,
                             __hip_bfloat16* __restrict__ o0, __hip_bfloat16* __restrict__ o1,
                             __hip_bfloat16* __restrict__ o2, __hip_bfloat16* __restrict__ o3,
                             int n4) {
    const float* in; __hip_bfloat16* out;
    switch (blockIdx.y) {
        case 0:  in = w0; out = o0; break;
        case 1:  in = w1; out = o1; break;
        case 2:  in = w2; out = o2; break;
        default: in = w3; out = o3; break;
    }
    int i = blockIdx.x * blockDim.x + threadIdx.x;
    if (i < n4) {
        float4 v = reinterpret_cast<const float4*>(in)[i];
        ushort4 u;
        u.x = bits_of(__float2bfloat16(v.x));
        u.y = bits_of(__float2bfloat16(v.y));
        u.z = bits_of(__float2bfloat16(v.z));
        u.w = bits_of(__float2bfloat16(v.w));
        reinterpret_cast<ushort4*>(out)[i] = u;
    }
}

// ---------------- GEMM (m97 structure): C[m][n] = sum_k A[m][k] * Bw[n][k] ----
template<int OUT_BF16>
__global__ __launch_bounds__(256) void gemm_bt(
    const __hip_bfloat16* __restrict__ A,
    const __hip_bfloat16* __restrict__ Bw,
    void* __restrict__ Cv, int M, int N, int K) {
    __shared__ __align__(16) __hip_bfloat16 As[128][32];
    __shared__ __align__(16) __hip_bfloat16 Bs[128][32];

    const int nbx = gridDim.x;
    const int lin = blockIdx.y * nbx + blockIdx.x;
    const int cpx = (nbx * gridDim.y) >> 3;
    const int swz = (lin & 7) * cpx + (lin >> 3);
    const int mBase = (swz / nbx) * 128, nBase = (swz % nbx) * 128;

    const int t = threadIdx.x;
    const int lane = t & 63, w = t >> 6;
    const int wr = (w >> 1) * 64, wc = (w & 1) * 64;
    const int lr = lane & 15, lk = (lane >> 4) * 8;
    const int sr = t >> 2, sc = (t & 3) * 8;
    const int wbase = w * 1024;

    f32x4 acc[4][4];
#pragma unroll
    for (int i = 0; i < 4; ++i)
#pragma unroll
        for (int j = 0; j < 4; ++j) acc[i][j] = (f32x4){0.f, 0.f, 0.f, 0.f};

    for (int kt = 0; kt < K; kt += 32) {
        __syncthreads();
#pragma unroll
        for (int it = 0; it < 2; ++it) {
            gload_lds16(A + (size_t)(mBase + sr + it * 64) * K + kt + sc,
                        (char*)&As[0][0] + wbase + it * 4096);
            gload_lds16(Bw + (size_t)(nBase + sr + it * 64) * K + kt + sc,
                        (char*)&Bs[0][0] + wbase + it * 4096);
        }
        __syncthreads();
        bf16x8 af[4], bfr[4];
#pragma unroll
        for (int i = 0; i < 4; ++i) {
            af[i]  = *reinterpret_cast<const bf16x8*>(&As[wr + i * 16 + lr][lk]);
            bfr[i] = *reinterpret_cast<const bf16x8*>(&Bs[wc + i * 16 + lr][lk]);
        }
#pragma unroll
        for (int i = 0; i < 4; ++i)
#pragma unroll
            for (int j = 0; j < 4; ++j)
                acc[i][j] = __builtin_amdgcn_mfma_f32_16x16x32_bf16(
                    af[i], bfr[j], acc[i][j], 0, 0, 0);
    }

#pragma unroll
    for (int i = 0; i < 4; ++i)
#pragma unroll
        for (int j = 0; j < 4; ++j)
#pragma unroll
            for (int v = 0; v < 4; ++v) {
                const int row = mBase + wr + i * 16 + (lane >> 4) * 4 + v;
                const int col = nBase + wc + j * 16 + lr;
                if (OUT_BF16)
                    ((__hip_bfloat16*)Cv)[(size_t)row * N + col] =
                        __float2bfloat16(acc[i][j][v]);
                else
                    ((float*)Cv)[(size_t)row * N + col] = acc[i][j][v];
            }
}

// ---------------- flash attention, paired causal blocks, KVBLK=128 ----------
// 4 waves x 32 q-rows (128 q/block). Block x handles qb=x (x+1 tiles of 128
// keys) AND qb=15-x (16-x tiles) -> uniform 17 tiles. Diagonal tile gates
// 32-key sub-tiles per wave (tt<=w, wave-uniform). Defer-max softmax.
__global__ __launch_bounds__(256) void attn_kernel(
    const __hip_bfloat16* __restrict__ QKV,   // [B*S][3E], Q|K|V blocks
    __hip_bfloat16* __restrict__ O) {         // [B*S][E]
    __shared__ __align__(16) __hip_bfloat16 Kl[128][64];   // 16KB, 128B rows
    __shared__ __align__(16) __hip_bfloat16 Vt[64][128];   // 16KB, 256B rows

    const int t = threadIdx.x, w = t >> 6, lane = t & 63;
    const int lq = lane & 31, hi = lane >> 5;
    const int h = blockIdx.y, b = blockIdx.z;

    const size_t rb = (size_t)b * SEQ;
    const __hip_bfloat16* Qg = QKV + rb * RQKV + h * HDIM;
    const __hip_bfloat16* Kg = QKV + rb * RQKV + E_DIM + h * HDIM;
    const __hip_bfloat16* Vg = QKV + rb * RQKV + 2 * E_DIM + h * HDIM;

    const float SCL2 = 0.04508422f;            // (1/32) * log2(e)

#pragma unroll 1
    for (int ph = 0; ph < 2; ++ph) {
        const int qb  = (ph == 0) ? (int)blockIdx.x : 15 - (int)blockIdx.x;
        const int qb0 = qb * 128;
        const int qw0 = qb0 + w * 32;
        const int qg  = qw0 + lq;

        bf16x8 aq[4];
#pragma unroll
        for (int d0 = 0; d0 < 4; ++d0)
            aq[d0] = *reinterpret_cast<const bf16x8*>(
                Qg + (size_t)qg * RQKV + d0 * 16 + hi * 8);

        f32x16 oa[2];
#pragma unroll
        for (int m = 0; m < 2; ++m)
#pragma unroll
            for (int r = 0; r < 16; ++r) oa[m][r] = 0.f;
        float m_run = -1e30f, l_run = 0.f;

        const int NT = qb + 1;
        for (int kt = 0; kt < NT; ++kt) {
            const int k0 = kt * 128;
            __syncthreads();   // previous tile's LDS reads done

            // --- stage K[128][64] swizzled via pre-swizzled global src ---
#pragma unroll
            for (int i = 0; i < 4; ++i) {
                const int r = w * 32 + i * 8 + (lane >> 3);
                const char* src = (const char*)(Kg + (size_t)(k0 + r) * RQKV) +
                                  (((lane & 7) * 16) ^ ((lane >> 3) << 4));
                gload_lds16(src, (char*)&Kl[0][0] + (w * 32 + i * 8) * 128);
            }
            // --- stage V transposed: Vt[d][k]; wave w does d rows w*16..+15,
            //     lane handles keys 2*lane, 2*lane+1; packed b32 writes ---
            {
                const __hip_bfloat16* vp =
                    Vg + (size_t)(k0 + 2 * lane) * RQKV + w * 16;
                bf16x8 va0 = *reinterpret_cast<const bf16x8*>(vp);
                bf16x8 va1 = *reinterpret_cast<const bf16x8*>(vp + 8);
                bf16x8 vb0 = *reinterpret_cast<const bf16x8*>(vp + RQKV);
                bf16x8 vb1 = *reinterpret_cast<const bf16x8*>(vp + RQKV + 8);
                char* vbase = (char*)&Vt[0][0];
#pragma unroll
                for (int j = 0; j < 8; ++j) {
                    const int d  = w * 16 + j;
                    const int d2 = d + 8;
                    const unsigned wb0 =
                        ((unsigned)(unsigned short)vb0[j] << 16) |
                        (unsigned short)va0[j];
                    const unsigned wb1 =
                        ((unsigned)(unsigned short)vb1[j] << 16) |
                        (unsigned short)va1[j];
                    *reinterpret_cast<unsigned*>(
                        vbase + d * 256 + ((lane * 4) ^ ((d & 7) << 4))) = wb0;
                    *reinterpret_cast<unsigned*>(
                        vbase + d2 * 256 + ((lane * 4) ^ ((d2 & 7) << 4))) = wb1;
                }
            }
            __syncthreads();

            const bool diag = (kt == qb);   // tile touching the causal diagonal

            // --- QK^T (swapped): S^T, lane owns q = lane&31; 4 key sub-tiles ---
            f32x16 sc2[4];
#pragma unroll
            for (int tt = 0; tt < 4; ++tt) {
                if (!diag || tt <= w) {
#pragma unroll
                    for (int r = 0; r < 16; ++r) sc2[tt][r] = 0.f;
                    const int kr = tt * 32 + lq;
                    const char* kbase =
                        reinterpret_cast<const char*>(&Kl[0][0]) + kr * 128;
                    const int swz = (kr & 7) << 4;
#pragma unroll
                    for (int d0 = 0; d0 < 4; ++d0) {
                        bf16x8 ak = *reinterpret_cast<const bf16x8*>(
                            kbase + ((d0 * 32 + hi * 16) ^ swz));
                        sc2[tt] = __builtin_amdgcn_mfma_f32_32x32x16_bf16(
                            ak, aq[d0], sc2[tt], 0, 0, 0);
                    }
                    // partial mask only on the diagonal sub-tile (tt == w)
                    if (diag && tt == w) {
#pragma unroll
                        for (int r = 0; r < 16; ++r) {
                            const int klocal = (r & 3) + 8 * (r >> 2) + 4 * hi;
                            if (klocal > lq) sc2[tt][r] = -1e30f;
                        }
                    }
                }
            }

            // --- online softmax with defer-max; max3-friendly tree ---
            float mt = -1e30f;
#pragma unroll
            for (int tt = 0; tt < 4; ++tt)
                if (!diag || tt <= w)
#pragma unroll
                    for (int r = 0; r < 16; r += 2)
                        mt = fmaxf(mt, fmaxf(sc2[tt][r], sc2[tt][r + 1]));
            mt = fmaxf(mt, __shfl_xor(mt, 32));
            if (!__all(mt <= m_run + 177.445f)) {   // growth > 8 in log2 domain
                const float mn = fmaxf(m_run, mt);
                const float corr = exp2f((m_run - mn) * SCL2);
                l_run *= corr;
                oa[0] *= corr;
                oa[1] *= corr;
                m_run = mn;
            }
            const float nb = -m_run * SCL2;
            float rsum = 0.f;
#pragma unroll
            for (int tt = 0; tt < 4; ++tt)
                if (!diag || tt <= w) {
                    float s0 = 0.f, s1 = 0.f, s2 = 0.f, s3 = 0.f;
#pragma unroll
                    for (int r = 0; r < 16; r += 4) {
                        float p0 = exp2f(__builtin_fmaf(sc2[tt][r], SCL2, nb));
                        float p1 = exp2f(__builtin_fmaf(sc2[tt][r + 1], SCL2, nb));
                        float p2 = exp2f(__builtin_fmaf(sc2[tt][r + 2], SCL2, nb));
                        float p3 = exp2f(__builtin_fmaf(sc2[tt][r + 3], SCL2, nb));
                        sc2[tt][r] = p0; sc2[tt][r + 1] = p1;
                        sc2[tt][r + 2] = p2; sc2[tt][r + 3] = p3;
                        s0 += p0; s1 += p1; s2 += p2; s3 += p3;
                    }
                    rsum += (s0 + s1) + (s2 + s3);
                }
            rsum += __shfl_xor(rsum, 32);
            l_run += rsum;

            // --- P -> bf16 B-frags via pack + permlane32_swap; PV ---
#pragma unroll
            for (int tt = 0; tt < 4; ++tt) {
                if (!diag || tt <= w) {
#pragma unroll
                    for (int sl = 0; sl < 2; ++sl) {
                        const int rbs = sl * 8;
                        const unsigned wA =
                            ((unsigned)bits_of(__float2bfloat16(sc2[tt][rbs + 1])) << 16) |
                            bits_of(__float2bfloat16(sc2[tt][rbs + 0]));
                        const unsigned wB =
                            ((unsigned)bits_of(__float2bfloat16(sc2[tt][rbs + 3])) << 16) |
                            bits_of(__float2bfloat16(sc2[tt][rbs + 2]));
                        const unsigned wC =
                            ((unsigned)bits_of(__float2bfloat16(sc2[tt][rbs + 5])) << 16) |
                            bits_of(__float2bfloat16(sc2[tt][rbs + 4]));
                        const unsigned wD =
                            ((unsigned)bits_of(__float2bfloat16(sc2[tt][rbs + 7])) << 16) |
                            bits_of(__float2bfloat16(sc2[tt][rbs + 6]));
                        const auto pA = __builtin_amdgcn_permlane32_swap(wA, wC, false, false);
                        const auto pB = __builtin_amdgcn_permlane32_swap(wB, wD, false, false);
                        union { unsigned u[4]; bf16x8 v; } pf;
                        pf.u[0] = pA[0]; pf.u[1] = pB[0];
                        pf.u[2] = pA[1]; pf.u[3] = pB[1];
                        const int ks = tt * 2 + sl;   // 16-key slice in [0,8)
                        const char* vtbase = (const char*)&Vt[0][0];
#pragma unroll
                        for (int m = 0; m < 2; ++m) {
                            const int dr = m * 32 + lq;
                            bf16x8 av = *reinterpret_cast<const bf16x8*>(
                                vtbase + dr * 256 +
                                ((ks * 32 + hi * 16) ^ ((dr & 7) << 4)));
                            oa[m] = __builtin_amdgcn_mfma_f32_32x32x16_bf16(
                                av, pf.v, oa[m], 0, 0, 0);
                        }
                    }
                }
            }
        }

        // --- epilogue for this phase ---
        const float inv = 1.f / l_run;
        __hip_bfloat16* Orow = O + (rb + qg) * E_DIM + h * HDIM;
#pragma unroll
        for (int m = 0; m < 2; ++m)
#pragma unroll
            for (int q4 = 0; q4 < 4; ++q4) {
                ushort4 pk;
                pk.x = bits_of(__float2bfloat16(oa[m][q4 * 4 + 0] * inv));
                pk.y = bits_of(__float2bfloat16(oa[m][q4 * 4 + 1] * inv));
                pk.z = bits_of(__float2bfloat16(oa[m][q4 * 4 + 2] * inv));
                pk.w = bits_of(__float2bfloat16(oa[m][q4 * 4 + 3] * inv));
                *reinterpret_cast<ushort4*>(Orow + m * 32 + q4 * 8 + 4 * hi) = pk;
            }
    }
}

// ---------------- launch ----------------
extern "C" void kernel_launch(void* const* d_in, const int* in_sizes, int n_in,
                              void* d_out, int out_size, void* d_ws, size_t ws_size,
                              hipStream_t stream) {
    const float* x  = (const float*)d_in[0];
    const float* wq = (const float*)d_in[1];
    const float* wk = (const float*)d_in[2];
    const float* wv = (const float*)d_in[3];
    const float* wo = (const float*)d_in[4];

    const size_t SZ_X = (size_t)BATCH * SEQ * E_DIM;   // 8388608
    const size_t SZ_W = (size_t)E_DIM * E_DIM;         // 1048576

    char* p = (char*)d_ws;
    __hip_bfloat16* xb    = (__hip_bfloat16*)p; p += SZ_X * 2;
    __hip_bfloat16* wqkvb = (__hip_bfloat16*)p; p += 3 * SZ_W * 2;   // [3E][E]
    __hip_bfloat16* wob   = (__hip_bfloat16*)p; p += SZ_W * 2;
    __hip_bfloat16* QKVb  = (__hip_bfloat16*)p; p += SZ_X * 3 * 2;   // [M][3E]
    __hip_bfloat16* attb  = (__hip_bfloat16*)p; p += SZ_X * 2;

    cast_kernel<<<(int)(SZ_X / 4 / 256), 256, 0, stream>>>(x, xb, (int)(SZ_X / 4));
    cast4_kernel<<<dim3((unsigned)(SZ_W / 4 / 256), 4), 256, 0, stream>>>(
        wq, wk, wv, wo, wqkvb, wqkvb + SZ_W, wqkvb + 2 * SZ_W, wob,
        (int)(SZ_W / 4));

    const int M = BATCH * SEQ;  // 8192
    gemm_bt<1><<<dim3(RQKV / 128, M / 128), 256, 0, stream>>>(
        xb, wqkvb, QKVb, M, RQKV, E_DIM);

    attn_kernel<<<dim3(SEQ / 256, NHEAD, BATCH), 256, 0, stream>>>(QKVb, attb);

    gemm_bt<0><<<dim3(E_DIM / 128, M / 128), 256, 0, stream>>>(
        attb, wob, d_out, M, E_DIM, E_DIM);
}